// Round 4
// baseline (234.334 us; speedup 1.0000x reference)
//
#include <hip/hip_runtime.h>

typedef unsigned short u16;
typedef unsigned int u32;
typedef short s16x8 __attribute__((ext_vector_type(8)));
typedef float f32x4 __attribute__((ext_vector_type(4)));
typedef float f32x16 __attribute__((ext_vector_type(16)));

#define HWN 4096
#define CC  256
#define C2  128

static __device__ __forceinline__ u16 f2bf(float f) {
    union { float f; u32 u; } c; c.f = f;
    u32 u = c.u;
    u32 r = (u + 0x7fffu + ((u >> 16) & 1u)) >> 16;
    return (u16)r;
}
static __device__ __forceinline__ float bf2f(u16 u) {
    union { u32 u; float f; } c; c.u = ((u32)u) << 16; return c.f;
}
static __device__ __forceinline__ u32 cvtpk(float lo, float hi) {
    u32 d;
    asm("v_cvt_pk_bf16_f32 %0, %1, %2" : "=v"(d) : "v"(lo), "v"(hi));
    return d;
}

// ---------------- K0: convert weights to bf16 ----------------
__global__ __launch_bounds__(256) void k_wcvt(
    const float* __restrict__ w_th, const float* __restrict__ w_pi,
    const float* __restrict__ w_g,  const float* __restrict__ w_out,
    u16* __restrict__ wthb, u16* __restrict__ wpib,
    u16* __restrict__ wgb,  u16* __restrict__ woutb)
{
    int i = blockIdx.x * 256 + threadIdx.x;
    wthb[i]  = f2bf(w_th[i]);
    wpib[i]  = f2bf(w_pi[i]);
    wgb[i]   = f2bf(w_g[i]);
    woutb[i] = f2bf(w_out[i]);
}

// ---------------- K1: MFMA projections (unchanged, proven) ----------------
__device__ __forceinline__ void load_afrag(const float* __restrict__ px, int g, s16x8 a[8]) {
    #pragma unroll
    for (int ks = 0; ks < 8; ++ks) {
        union { s16x8 v; u16 u[8]; } c;
        #pragma unroll
        for (int j = 0; j < 8; ++j)
            c.u[j] = f2bf(px[(size_t)(ks*32 + g*8 + j) * HWN]);
        a[ks] = c.v;
    }
}

__device__ __forceinline__ void proj_gemm(const s16x8 a[8], const u16* __restrict__ wb,
                                          const float* __restrict__ bias,
                                          int m16, int g, f32x4 acc[8]) {
    #pragma unroll
    for (int nb = 0; nb < 8; ++nb) {
        float bv = bias[nb*16 + m16];
        acc[nb] = (f32x4){bv, bv, bv, bv};
    }
    #pragma unroll
    for (int ks = 0; ks < 8; ++ks) {
        #pragma unroll
        for (int nb = 0; nb < 8; ++nb) {
            s16x8 bb = *(const s16x8*)&wb[(size_t)(nb*16 + m16)*CC + ks*32 + g*8];
            acc[nb] = __builtin_amdgcn_mfma_f32_16x16x32_bf16(a[ks], bb, acc[nb], 0, 0, 0);
        }
    }
}

__global__ __launch_bounds__(256) void k_projM(
    const float* __restrict__ x1, const float* __restrict__ x2,
    const u16* __restrict__ wthb, const float* __restrict__ b_th,
    const u16* __restrict__ wpib, const float* __restrict__ b_pi,
    const u16* __restrict__ wgb,  const float* __restrict__ b_g,
    u16* __restrict__ e1t, u16* __restrict__ e2t, u16* __restrict__ g2c)
{
    __shared__ u16 gs[C2][72];
    const int tid  = threadIdx.x;
    const int b    = blockIdx.x >> 6;
    const int q0   = (blockIdx.x & 63) * 64;
    const int wid  = __builtin_amdgcn_readfirstlane(tid >> 6);
    const int lane = tid & 63;
    const int m16  = lane & 15;
    const int g    = lane >> 4;

    s16x8 a[8];
    f32x4 acc[8];

    const float* px1 = x1 + (size_t)b*CC*HWN + q0 + wid*16 + m16;
    load_afrag(px1, g, a);
    proj_gemm(a, wthb, b_th, m16, g, acc);
    #pragma unroll
    for (int nb = 0; nb < 8; ++nb)
        #pragma unroll
        for (int r = 0; r < 4; ++r)
            e1t[((size_t)b*HWN + q0 + wid*16 + g*4 + r)*C2 + nb*16 + m16] = f2bf(acc[nb][r]);

    const float* px2 = x2 + (size_t)b*CC*HWN + q0 + wid*16 + m16;
    load_afrag(px2, g, a);
    proj_gemm(a, wpib, b_pi, m16, g, acc);
    #pragma unroll
    for (int nb = 0; nb < 8; ++nb)
        #pragma unroll
        for (int r = 0; r < 4; ++r)
            e2t[((size_t)b*HWN + q0 + wid*16 + g*4 + r)*C2 + nb*16 + m16] = f2bf(acc[nb][r]);

    proj_gemm(a, wgb, b_g, m16, g, acc);
    #pragma unroll
    for (int nb = 0; nb < 8; ++nb)
        #pragma unroll
        for (int r = 0; r < 4; ++r)
            gs[nb*16 + m16][wid*16 + g*4 + r] = f2bf(acc[nb][r]);
    __syncthreads();
    #pragma unroll
    for (int r = 0; r < 4; ++r) {
        int idx = r*256 + tid;
        int c2 = idx >> 3, q8 = idx & 7;
        int4 v = *(const int4*)&gs[c2][q8*8];
        *(int4*)&g2c[((size_t)b*C2 + c2)*HWN + q0 + q8*8] = v;
    }
}

// ---------------- K2: flash core — 32x32 MFMA, swapped QK^T, in-reg softmax ----
// Block: 4 waves x 32q = 128 q-rows; k-split 2 (seg), 32 k-tiles of 64.
// S^T = mfma(A=e2, B=e1): lane holds S[attnk][q=lane&31]; softmax in regs;
// P -> PV B-frag via cvt_pk_bf16 + v_permlane32_swap; PV: O^T = mfma(A=g2, B=P).
__global__ __launch_bounds__(256, 2) void k_flash(
    const u16* __restrict__ e1t, const u16* __restrict__ e2t,
    const u16* __restrict__ g2c,
    u16* __restrict__ outp0, u16* __restrict__ outp1, float* __restrict__ ms)
{
    __shared__ u16 e2s[2][64*128];   // [k][c2]  rows 256B, 16B-granule XOR swizzle
    __shared__ u16 g2s[2][128*64];   // [c2][k]  rows 128B, swizzled

    const int tid  = threadIdx.x;
    const int bid  = ((blockIdx.x & 7) << 6) | (blockIdx.x >> 3);  // XCD-chunked
    const int b    = bid >> 6;
    const int qb   = (bid >> 1) & 31;
    const int seg  = bid & 1;
    const int q0   = qb * 128;
    const int wid  = __builtin_amdgcn_readfirstlane(tid >> 6);
    const int lane = tid & 63;
    const int l31  = lane & 31;
    const int h    = lane >> 5;
    const int swz  = (l31 & 7) << 3;     // u16-index XOR (16B granule)

    // e1 B-frags (q side), hoisted in regs for whole kernel
    s16x8 bq[8];
    {
        const u16* p = e1t + ((size_t)b*HWN + q0 + wid*32 + l31)*C2 + h*8;
        #pragma unroll
        for (int ks = 0; ks < 8; ++ks) bq[ks] = *(const s16x8*)(p + ks*16);
    }

    f32x16 accT[4];
    #pragma unroll
    for (int i = 0; i < 4; ++i)
        accT[i] = (f32x16){0,0,0,0,0,0,0,0,0,0,0,0,0,0,0,0};
    float m_w = -INFINITY, s_w = 0.f;

    const u16* e2base = e2t + (size_t)b*HWN*C2;
    const u16* g2base = g2c + (size_t)b*C2*HWN;
    const int er = tid >> 4, ec = tid & 15;
    const int gr = tid >> 3, gc = tid & 7;
    int ew[4], gw[4];
    #pragma unroll
    for (int r = 0; r < 4; ++r) {
        int row = r*16 + er; ew[r] = (row*128 + ec*8) ^ ((row & 7) << 3);
        int rw  = r*32 + gr; gw[r] = (rw*64  + gc*8) ^ ((rw  & 7) << 3);
    }

    // prologue: tile 0 -> buf 0
    int4 se[4], sg[4];
    {
        const int k0 = seg*2048;
        #pragma unroll
        for (int r = 0; r < 4; ++r)
            se[r] = *(const int4*)(e2base + (size_t)(k0 + r*16 + er)*C2 + ec*8);
        #pragma unroll
        for (int r = 0; r < 4; ++r)
            sg[r] = *(const int4*)(g2base + (size_t)(r*32 + gr)*HWN + k0 + gc*8);
        #pragma unroll
        for (int r = 0; r < 4; ++r) *(int4*)&e2s[0][ew[r]] = se[r];
        #pragma unroll
        for (int r = 0; r < 4; ++r) *(int4*)&g2s[0][gw[r]] = sg[r];
    }

    for (int it = 0; it < 32; ++it) {
        const int cur = it & 1;
        __syncthreads();
        const bool more = (it + 1 < 32);
        if (more) {                      // issue next-tile loads (fly under compute)
            const int k0n = seg*2048 + (it+1)*64;
            #pragma unroll
            for (int r = 0; r < 4; ++r)
                se[r] = *(const int4*)(e2base + (size_t)(k0n + r*16 + er)*C2 + ec*8);
            #pragma unroll
            for (int r = 0; r < 4; ++r)
                sg[r] = *(const int4*)(g2base + (size_t)(r*32 + gr)*HWN + k0n + gc*8);
        }

        // ---- QK^T: S^T[64 attnk][32 q], contraction over c2=128
        f32x16 sr[2];
        sr[0] = (f32x16){0,0,0,0,0,0,0,0,0,0,0,0,0,0,0,0};
        sr[1] = (f32x16){0,0,0,0,0,0,0,0,0,0,0,0,0,0,0,0};
        __builtin_amdgcn_s_setprio(1);
        #pragma unroll
        for (int ks = 0; ks < 8; ++ks) {
            #pragma unroll
            for (int mt = 0; mt < 2; ++mt) {
                const int row = mt*32 + l31;
                s16x8 afr = *(const s16x8*)&e2s[cur][row*128 + ((ks*16 + h*8) ^ swz)];
                sr[mt] = __builtin_amdgcn_mfma_f32_32x32x16_bf16(afr, bq[ks], sr[mt], 0, 0, 0);
            }
        }
        __builtin_amdgcn_s_setprio(0);

        // ---- softmax in registers (wave-level running max, defer-rescale THR=8)
        float tm = -INFINITY;
        #pragma unroll
        for (int mt = 0; mt < 2; ++mt)
            #pragma unroll
            for (int r = 0; r < 16; ++r) tm = fmaxf(tm, sr[mt][r]);
        #pragma unroll
        for (int off = 32; off >= 1; off >>= 1) tm = fmaxf(tm, __shfl_xor(tm, off));
        if (tm > m_w + 8.f) {
            const float sc = __expf(m_w - tm);
            s_w *= sc;
            #pragma unroll
            for (int mt = 0; mt < 4; ++mt)
                #pragma unroll
                for (int r = 0; r < 16; ++r) accT[mt][r] *= sc;
            m_w = tm;
        }
        float psum = 0.f;
        #pragma unroll
        for (int mt = 0; mt < 2; ++mt)
            #pragma unroll
            for (int r = 0; r < 16; ++r) {
                float p = __expf(sr[mt][r] - m_w);
                sr[mt][r] = p;
                psum += p;
            }
        s_w += psum;

        // ---- PV: O^T[128 c2][32 q] += g2[c2][attnk] * P[attnk][q]
        __builtin_amdgcn_s_setprio(1);
        #pragma unroll
        for (int ks = 0; ks < 4; ++ks) {
            const int mt_s = ks >> 1, rb = (ks & 1) * 8;
            u32 wA = cvtpk(sr[mt_s][rb+0], sr[mt_s][rb+1]);
            u32 wB = cvtpk(sr[mt_s][rb+2], sr[mt_s][rb+3]);
            u32 wC = cvtpk(sr[mt_s][rb+4], sr[mt_s][rb+5]);
            u32 wD = cvtpk(sr[mt_s][rb+6], sr[mt_s][rb+7]);
            asm volatile("v_permlane32_swap_b32 %0, %1" : "+v"(wA), "+v"(wC));
            asm volatile("v_permlane32_swap_b32 %0, %1" : "+v"(wB), "+v"(wD));
            union { u32 w[4]; s16x8 v; } pf;
            pf.w[0] = wA; pf.w[1] = wB; pf.w[2] = wC; pf.w[3] = wD;
            #pragma unroll
            for (int mt = 0; mt < 4; ++mt) {
                const int row = mt*32 + l31;
                s16x8 gfr = *(const s16x8*)&g2s[cur][row*64 + ((ks*16 + h*8) ^ swz)];
                accT[mt] = __builtin_amdgcn_mfma_f32_32x32x16_bf16(gfr, pf.v, accT[mt], 0, 0, 0);
            }
        }
        __builtin_amdgcn_s_setprio(0);

        if (more) {                      // write next tile into other buffer
            #pragma unroll
            for (int r = 0; r < 4; ++r) *(int4*)&e2s[cur ^ 1][ew[r]] = se[r];
            #pragma unroll
            for (int r = 0; r < 4; ++r) *(int4*)&g2s[cur ^ 1][gw[r]] = sg[r];
        }
    }

    // ---- epilogue: reduce s_w, write (m,s), transpose O^T->[q][c2] via LDS bounce
    #pragma unroll
    for (int off = 32; off >= 1; off >>= 1) s_w += __shfl_xor(s_w, off);
    if (lane == 0) {
        int idx = b*256 + seg*128 + qb*4 + wid;
        ms[idx*2 + 0] = m_w;
        ms[idx*2 + 1] = s_w;
    }
    const float inv_s = 1.f / s_w;
    __syncthreads();                     // all waves done with compute buffers
    u16* lb = &e2s[0][0] + wid*4096;     // private 8 KiB per wave
    #pragma unroll
    for (int mt = 0; mt < 4; ++mt)
        #pragma unroll
        for (int p = 0; p < 8; ++p) {
            u32 w = cvtpk(accT[mt][2*p] * inv_s, accT[mt][2*p+1] * inv_s);
            int c2 = mt*32 + ((2*p) & 3) + 8*((2*p) >> 2) + 4*h;
            int idx = (l31*128 + c2) ^ swz;     // same 16B-granule involution
            *(u32*)&lb[idx] = w;
        }
    // wave-local read-back (compiler inserts lgkmcnt), coalesced b128 store
    u16* op = seg ? outp1 : outp0;
    #pragma unroll
    for (int i = 0; i < 8; ++i) {
        int cf = i*64 + lane;
        int row = cf >> 4, ch = cf & 15;
        int4 v = *(const int4*)&lb[(row*128 + ch*8) ^ ((row & 7) << 3)];
        *(int4*)&op[((size_t)b*HWN + q0 + wid*32 + row)*C2 + ch*8] = v;
    }
}

// ---------------- K3: per-batch (M, Z) from 256 (m,s) pairs ----------------
__global__ void k_mz(const float* __restrict__ ms, float* __restrict__ mz)
{
    __shared__ float rmax[4], rsum[4];
    const int b = blockIdx.x, tid = threadIdx.x;
    const int lane = tid & 63, wid = tid >> 6;
    float m = ms[((size_t)b*256 + tid)*2 + 0];
    float s = ms[((size_t)b*256 + tid)*2 + 1];
    float mm = m;
    #pragma unroll
    for (int off = 32; off >= 1; off >>= 1) mm = fmaxf(mm, __shfl_xor(mm, off));
    if (lane == 0) rmax[wid] = mm;
    __syncthreads();
    float M = fmaxf(fmaxf(rmax[0], rmax[1]), fmaxf(rmax[2], rmax[3]));
    float z = s * __expf(m - M);
    #pragma unroll
    for (int off = 32; off >= 1; off >>= 1) z += __shfl_xor(z, off);
    if (lane == 0) rsum[wid] = z;
    __syncthreads();
    if (tid == 0) { mz[b*2] = M; mz[b*2+1] = rsum[0]+rsum[1]+rsum[2]+rsum[3]; }
}

// ---------------- K4: combine k-split partials + final conv + residual --------
__global__ __launch_bounds__(256) void k_outM(
    const u16* __restrict__ outp0, const u16* __restrict__ outp1,
    const float* __restrict__ ms, const float* __restrict__ mz,
    const u16* __restrict__ woutb, const float* __restrict__ b_out,
    const float* __restrict__ x1, float* __restrict__ out)
{
    const int tid  = threadIdx.x;
    const int b    = blockIdx.x >> 6;
    const int q0   = (blockIdx.x & 63) * 64;
    const int wv   = tid >> 6;
    const int lane = tid & 63;
    const int m16  = lane & 15;
    const int g    = lane >> 4;
    const int q    = q0 + wv*16 + m16;

    const float M    = mz[b*2];
    const float invZ = 1.f / mz[b*2+1];
    const int idx5   = (q0 >> 5) + (wv >> 1);
    const float a0 = ms[(b*256 + idx5)*2+1]       * __expf(ms[(b*256 + idx5)*2]       - M) * invZ;
    const float a1 = ms[(b*256 + 128 + idx5)*2+1] * __expf(ms[(b*256 + 128 + idx5)*2] - M) * invZ;

    s16x8 bfr[4];
    #pragma unroll
    for (int ks = 0; ks < 4; ++ks) {
        union { s16x8 v; u16 u[8]; } o0, o1, oc;
        o0.v = *(const s16x8*)&outp0[((size_t)b*HWN + q)*C2 + ks*32 + g*8];
        o1.v = *(const s16x8*)&outp1[((size_t)b*HWN + q)*C2 + ks*32 + g*8];
        #pragma unroll
        for (int j = 0; j < 8; ++j)
            oc.u[j] = f2bf(a0*bf2f(o0.u[j]) + a1*bf2f(o1.u[j]));
        bfr[ks] = oc.v;
    }

    f32x4 acc[16];
    #pragma unroll
    for (int cb = 0; cb < 16; ++cb) acc[cb] = (f32x4){0.f,0.f,0.f,0.f};
    #pragma unroll
    for (int ks = 0; ks < 4; ++ks) {
        #pragma unroll
        for (int cb = 0; cb < 16; ++cb) {
            s16x8 afr = *(const s16x8*)&woutb[(size_t)(cb*16 + m16)*C2 + ks*32 + g*8];
            acc[cb] = __builtin_amdgcn_mfma_f32_16x16x32_bf16(afr, bfr[ks], acc[cb], 0, 0, 0);
        }
    }

    #pragma unroll
    for (int cb = 0; cb < 16; ++cb) {
        f32x4 bb = *(const f32x4*)&b_out[cb*16 + g*4];
        #pragma unroll
        for (int r = 0; r < 4; ++r) {
            int co = cb*16 + g*4 + r;
            size_t o = ((size_t)b*CC + co)*HWN + q;
            out[o] = acc[cb][r] + bb[r] + x1[o];
        }
    }
}

extern "C" void kernel_launch(void* const* d_in, const int* in_sizes, int n_in,
                              void* d_out, int out_size, void* d_ws, size_t ws_size,
                              hipStream_t stream)
{
    const float* x1   = (const float*)d_in[0];
    const float* x2   = (const float*)d_in[1];
    const float* w_th = (const float*)d_in[2];
    const float* b_th = (const float*)d_in[3];
    const float* w_pi = (const float*)d_in[4];
    const float* b_pi = (const float*)d_in[5];
    const float* w_g  = (const float*)d_in[6];
    const float* b_g  = (const float*)d_in[7];
    const float* w_out= (const float*)d_in[8];
    const float* b_out= (const float*)d_in[9];
    float* out = (float*)d_out;

    char* ws = (char*)d_ws;
    u16*   e1t  = (u16*)(ws);                    // 8 MiB  bf16 [B][HW][C2]
    u16*   e2t  = (u16*)(ws + 8388608);          // 8 MiB  bf16 [B][HW][C2]
    u16*   g2c  = (u16*)(ws + 16777216);         // 8 MiB  bf16 [B][C2][HW]
    u16*   outp0= (u16*)(ws + 25165824);         // 8 MiB  bf16 seg0 partial
    u16*   outp1= (u16*)(ws + 33554432);         // 8 MiB  bf16 seg1 partial
    float* ms   = (float*)(ws + 41943040);       // 16 KiB f32  [B][256][2]
    float* mz   = (float*)(ws + 41959424);       // 64 B   f32  [B][2]
    u16*   wthb = (u16*)(ws + 41959488);         // 64 KiB bf16 [C2][CC]
    u16*   wpib = (u16*)(ws + 42025024);         // 64 KiB
    u16*   wgb  = (u16*)(ws + 42090560);         // 64 KiB
    u16*   woutb= (u16*)(ws + 42156096);         // 64 KiB bf16 [CC][C2]

    k_wcvt <<<dim3(128), dim3(256), 0, stream>>>(w_th, w_pi, w_g, w_out, wthb, wpib, wgb, woutb);
    k_projM<<<dim3(512), dim3(256), 0, stream>>>(x1, x2, wthb, b_th, wpib, b_pi, wgb, b_g,
                                                 e1t, e2t, g2c);
    k_flash<<<dim3(512), dim3(256), 0, stream>>>(e1t, e2t, g2c, outp0, outp1, ms);
    k_mz   <<<dim3(8),   dim3(256), 0, stream>>>(ms, mz);
    k_outM <<<dim3(512), dim3(256), 0, stream>>>(outp0, outp1, ms, mz, woutb, b_out, x1, out);
}